// Round 1
// baseline (1559.919 us; speedup 1.0000x reference)
//
#include <hip/hip_runtime.h>
#include <math.h>

// GraphConv x5 (DGL norm='both') on MI355X.
// Pipeline per call (deterministic work):
//   1. degree counts (atomics, int)           -> dout_cnt, din_cnt
//   2. inv-sqrt degrees (clamped to >=1)      -> dout_is, din_is
//   3. exclusive scan of din_cnt              -> row_ptr (CSR by dst)
//   4. edge scatter into CSR slots            -> csr_src
//   5. per layer: lin (x*dout_is)@W -> h ; gather over in-edges fused with
//      (*din_is + b [+leakyrelu]) -> next x.  Ping-pong buffers A/B.

#define LRELU_SLOPE 0.01f

// ---------------- preprocessing ----------------

__global__ void k_degcount(const int* __restrict__ src, const int* __restrict__ dst,
                           int E, unsigned* __restrict__ dout_cnt, unsigned* __restrict__ din_cnt) {
    int e = blockIdx.x * blockDim.x + threadIdx.x;
    if (e < E) {
        atomicAdd(&dout_cnt[src[e]], 1u);
        atomicAdd(&din_cnt[dst[e]], 1u);
    }
}

__global__ void k_invsqrt(const unsigned* __restrict__ cnt, float* __restrict__ inv, int n) {
    int i = blockIdx.x * blockDim.x + threadIdx.x;
    if (i < n) {
        float d = fmaxf((float)cnt[i], 1.0f);
        inv[i] = 1.0f / sqrtf(d);
    }
}

// blocked Hillis-Steele inclusive scan, 256/block
__global__ void k_scan_block(const unsigned* __restrict__ in, unsigned* __restrict__ out,
                             unsigned* __restrict__ bsum, int n) {
    __shared__ unsigned s[256];
    int g = blockIdx.x * 256 + threadIdx.x;
    unsigned v = (g < n) ? in[g] : 0u;
    s[threadIdx.x] = v;
    __syncthreads();
    for (int off = 1; off < 256; off <<= 1) {
        unsigned t = (threadIdx.x >= (unsigned)off) ? s[threadIdx.x - off] : 0u;
        __syncthreads();
        s[threadIdx.x] += t;
        __syncthreads();
    }
    if (g < n) out[g] = s[threadIdx.x];
    if (threadIdx.x == 255) bsum[blockIdx.x] = s[255];
}

// single-block scan of block sums -> exclusive offsets (n <= 1024)
__global__ void k_scan_single(unsigned* __restrict__ bsum, int n) {
    __shared__ unsigned s[1024];
    int t = threadIdx.x;
    s[t] = (t < n) ? bsum[t] : 0u;
    __syncthreads();
    for (int off = 1; off < 1024; off <<= 1) {
        unsigned v = (t >= off) ? s[t - off] : 0u;
        __syncthreads();
        s[t] += v;
        __syncthreads();
    }
    if (t < n) bsum[t] = (t == 0) ? 0u : s[t - 1];
}

__global__ void k_finalize_rowptr(const unsigned* __restrict__ scanned, const unsigned* __restrict__ boff,
                                  unsigned* __restrict__ row_ptr, int n) {
    int g = blockIdx.x * blockDim.x + threadIdx.x;
    if (g < n) row_ptr[g + 1] = scanned[g] + boff[g >> 8];
    if (g == 0) row_ptr[0] = 0u;
}

__global__ void k_csr(const int* __restrict__ src, const int* __restrict__ dst, int E,
                      const unsigned* __restrict__ row_ptr, unsigned* __restrict__ cursor,
                      int* __restrict__ csr) {
    int e = blockIdx.x * blockDim.x + threadIdx.x;
    if (e < E) {
        int d = dst[e];
        unsigned slot = atomicAdd(&cursor[d], 1u);
        csr[row_ptr[d] + slot] = src[e];
    }
}

// ---------------- layers ----------------

// layer1: fin=4 -> fout=128, thread per (node, j)
__global__ void k_lin1(const float* __restrict__ x, const float* __restrict__ W,
                       const float* __restrict__ dout_is, float* __restrict__ h, int n) {
    int t = blockIdx.x * blockDim.x + threadIdx.x;
    int i = t >> 7, j = t & 127;
    if (i >= n) return;
    float s = dout_is[i];
    float4 xv = *reinterpret_cast<const float4*>(x + (size_t)i * 4);
    float acc = xv.x * W[0 * 128 + j] + xv.y * W[1 * 128 + j] + xv.z * W[2 * 128 + j] + xv.w * W[3 * 128 + j];
    h[(size_t)i * 128 + j] = acc * s;
}

// fin=128 -> fout=128. W staged in LDS (64KB), 4-node register blocking:
// each LDS W element reused 4x. block=256: 2 groups of 128 j-threads,
// group g handles nodes base+4g .. base+4g+3.
__global__ __launch_bounds__(256) void k_lin128(const float* __restrict__ x, const float* __restrict__ W,
                                                const float* __restrict__ dout_is, float* __restrict__ h, int n) {
    __shared__ float Ws[128 * 128];
    for (int idx = threadIdx.x; idx < 128 * 128; idx += 256) Ws[idx] = W[idx];
    __syncthreads();
    int j = threadIdx.x & 127;
    int g = threadIdx.x >> 7;  // 0..1
    for (int base = blockIdx.x * 8; base < n; base += gridDim.x * 8) {
        int i0 = base + g * 4;
        if (i0 + 3 < n) {
            const float* x0 = x + (size_t)i0 * 128;
            const float* x1 = x0 + 128;
            const float* x2 = x0 + 256;
            const float* x3 = x0 + 384;
            float acc0 = 0.f, acc1 = 0.f, acc2 = 0.f, acc3 = 0.f;
#pragma unroll 8
            for (int k = 0; k < 128; k += 4) {
                float4 a0 = *reinterpret_cast<const float4*>(x0 + k);
                float4 a1 = *reinterpret_cast<const float4*>(x1 + k);
                float4 a2 = *reinterpret_cast<const float4*>(x2 + k);
                float4 a3 = *reinterpret_cast<const float4*>(x3 + k);
                float w0 = Ws[(k + 0) * 128 + j];
                float w1 = Ws[(k + 1) * 128 + j];
                float w2 = Ws[(k + 2) * 128 + j];
                float w3 = Ws[(k + 3) * 128 + j];
                acc0 += a0.x * w0 + a0.y * w1 + a0.z * w2 + a0.w * w3;
                acc1 += a1.x * w0 + a1.y * w1 + a1.z * w2 + a1.w * w3;
                acc2 += a2.x * w0 + a2.y * w1 + a2.z * w2 + a2.w * w3;
                acc3 += a3.x * w0 + a3.y * w1 + a3.z * w2 + a3.w * w3;
            }
            h[(size_t)(i0 + 0) * 128 + j] = acc0 * dout_is[i0 + 0];
            h[(size_t)(i0 + 1) * 128 + j] = acc1 * dout_is[i0 + 1];
            h[(size_t)(i0 + 2) * 128 + j] = acc2 * dout_is[i0 + 2];
            h[(size_t)(i0 + 3) * 128 + j] = acc3 * dout_is[i0 + 3];
        } else {
            for (int i = i0; i < n && i < i0 + 4; ++i) {
                const float* xr = x + (size_t)i * 128;
                float acc = 0.f;
                for (int k = 0; k < 128; ++k) acc += xr[k] * Ws[k * 128 + j];
                h[(size_t)i * 128 + j] = acc * dout_is[i];
            }
        }
    }
}

// gather + normalize + bias (+ leaky relu) fused. block=128 per node.
__global__ __launch_bounds__(128) void k_gather128(const float* __restrict__ h, const int* __restrict__ csr,
                                                   const unsigned* __restrict__ row_ptr,
                                                   const float* __restrict__ din_is, const float* __restrict__ b,
                                                   float* __restrict__ xo, int n, int relu) {
    int i = blockIdx.x;
    if (i >= n) return;
    int j = threadIdx.x;
    unsigned beg = row_ptr[i], end = row_ptr[i + 1];
    float acc = 0.f;
    for (unsigned e = beg; e < end; ++e) {
        int s = csr[e];
        acc += h[(size_t)s * 128 + j];
    }
    float v = acc * din_is[i] + b[j];
    if (relu) v = (v >= 0.f) ? v : LRELU_SLOPE * v;
    xo[(size_t)i * 128 + j] = v;
}

// fin=128 -> fout=3: block of 128 per node, wave-shuffle reduce.
__global__ __launch_bounds__(128) void k_lin5(const float* __restrict__ x, const float* __restrict__ W,
                                              const float* __restrict__ dout_is, float* __restrict__ h, int n) {
    int i = blockIdx.x;
    if (i >= n) return;
    int k = threadIdx.x;
    float xk = x[(size_t)i * 128 + k] * dout_is[i];
    float p0 = xk * W[k * 3 + 0];
    float p1 = xk * W[k * 3 + 1];
    float p2 = xk * W[k * 3 + 2];
    for (int off = 32; off; off >>= 1) {
        p0 += __shfl_down(p0, off);
        p1 += __shfl_down(p1, off);
        p2 += __shfl_down(p2, off);
    }
    __shared__ float part[2][3];
    if ((k & 63) == 0) {
        int w = k >> 6;
        part[w][0] = p0; part[w][1] = p1; part[w][2] = p2;
    }
    __syncthreads();
    if (k < 3) h[(size_t)i * 3 + k] = part[0][k] + part[1][k];
}

__global__ void k_gather3(const float* __restrict__ h, const int* __restrict__ csr,
                          const unsigned* __restrict__ row_ptr, const float* __restrict__ din_is,
                          const float* __restrict__ b, float* __restrict__ out, int n) {
    int i = blockIdx.x * blockDim.x + threadIdx.x;
    if (i >= n) return;
    unsigned beg = row_ptr[i], end = row_ptr[i + 1];
    float a0 = 0.f, a1 = 0.f, a2 = 0.f;
    for (unsigned e = beg; e < end; ++e) {
        int s = csr[e];
        a0 += h[(size_t)s * 3 + 0];
        a1 += h[(size_t)s * 3 + 1];
        a2 += h[(size_t)s * 3 + 2];
    }
    float di = din_is[i];
    out[(size_t)i * 3 + 0] = a0 * di + b[0];
    out[(size_t)i * 3 + 1] = a1 * di + b[1];
    out[(size_t)i * 3 + 2] = a2 * di + b[2];
}

// ---------------- launch ----------------

extern "C" void kernel_launch(void* const* d_in, const int* in_sizes, int n_in,
                              void* d_out, int out_size, void* d_ws, size_t ws_size,
                              hipStream_t stream) {
    const float* features = (const float*)d_in[0];
    const int* esrc = (const int*)d_in[1];
    const int* edst = (const int*)d_in[2];
    const float* W1 = (const float*)d_in[3];  const float* b1 = (const float*)d_in[4];
    const float* W2 = (const float*)d_in[5];  const float* b2 = (const float*)d_in[6];
    const float* W3 = (const float*)d_in[7];  const float* b3 = (const float*)d_in[8];
    const float* W4 = (const float*)d_in[9];  const float* b4 = (const float*)d_in[10];
    const float* W5 = (const float*)d_in[11]; const float* b5 = (const float*)d_in[12];

    const int N = in_sizes[0] / 4;
    const int E = in_sizes[1];

    // workspace carve-up (256B aligned)
    size_t off = 0;
    auto carve = [&](size_t bytes) -> void* {
        void* p = (char*)d_ws + off;
        off = (off + bytes + 255) & ~(size_t)255;
        return p;
    };
    float*    A        = (float*)carve((size_t)N * 128 * 4);
    float*    B        = (float*)carve((size_t)N * 128 * 4);
    int*      csr      = (int*)carve((size_t)E * 4);
    unsigned* row_ptr  = (unsigned*)carve((size_t)(N + 1) * 4);
    unsigned* cursor   = (unsigned*)carve((size_t)N * 4);
    unsigned* dout_cnt = (unsigned*)carve((size_t)N * 4);
    unsigned* din_cnt  = (unsigned*)carve((size_t)N * 4);
    float*    dout_is  = (float*)carve((size_t)N * 4);
    float*    din_is   = (float*)carve((size_t)N * 4);
    unsigned* scan_tmp = (unsigned*)carve((size_t)N * 4);
    unsigned* bsum     = (unsigned*)carve(4096);
    (void)ws_size;

    hipMemsetAsync(dout_cnt, 0, (size_t)N * 4, stream);
    hipMemsetAsync(din_cnt, 0, (size_t)N * 4, stream);
    hipMemsetAsync(cursor, 0, (size_t)N * 4, stream);

    k_degcount<<<(E + 255) / 256, 256, 0, stream>>>(esrc, edst, E, dout_cnt, din_cnt);
    k_invsqrt<<<(N + 255) / 256, 256, 0, stream>>>(dout_cnt, dout_is, N);
    k_invsqrt<<<(N + 255) / 256, 256, 0, stream>>>(din_cnt, din_is, N);

    int nscan = (N + 255) / 256;
    k_scan_block<<<nscan, 256, 0, stream>>>(din_cnt, scan_tmp, bsum, N);
    k_scan_single<<<1, 1024, 0, stream>>>(bsum, nscan);
    k_finalize_rowptr<<<(N + 255) / 256, 256, 0, stream>>>(scan_tmp, bsum, row_ptr, N);
    k_csr<<<(E + 255) / 256, 256, 0, stream>>>(esrc, edst, E, row_ptr, cursor, csr);

    // layer 1: 4 -> 128
    k_lin1<<<((size_t)N * 128 + 255) / 256, 256, 0, stream>>>(features, W1, dout_is, B, N);
    k_gather128<<<N, 128, 0, stream>>>(B, csr, row_ptr, din_is, b1, A, N, 1);
    // layers 2-4: 128 -> 128
    k_lin128<<<2048, 256, 0, stream>>>(A, W2, dout_is, B, N);
    k_gather128<<<N, 128, 0, stream>>>(B, csr, row_ptr, din_is, b2, A, N, 1);
    k_lin128<<<2048, 256, 0, stream>>>(A, W3, dout_is, B, N);
    k_gather128<<<N, 128, 0, stream>>>(B, csr, row_ptr, din_is, b3, A, N, 1);
    k_lin128<<<2048, 256, 0, stream>>>(A, W4, dout_is, B, N);
    k_gather128<<<N, 128, 0, stream>>>(B, csr, row_ptr, din_is, b4, A, N, 1);
    // layer 5: 128 -> 3
    k_lin5<<<N, 128, 0, stream>>>(A, W5, dout_is, B, N);
    k_gather3<<<(N + 255) / 256, 256, 0, stream>>>(B, csr, row_ptr, din_is, b5, (float*)d_out, N);
}

// Round 2
// 1257.640 us; speedup vs baseline: 1.2404x; 1.2404x over previous
//
#include <hip/hip_runtime.h>
#include <math.h>

// GraphConv x5 (DGL norm='both') on MI355X.
// Layer algebra: agg commutes with W-multiply, so layer 1 aggregates the
// 4-wide features FIRST (32x less gathered data), then does the 4->128 GEMM.
// Layers 2-4: lin128 (cache-resident W, 8-node register blocking), then
// float4 gather fused with din_is*acc+b+leakyrelu. Layer 5: 128->3 GEMM
// (32 lanes/node) then 3-wide gather.

#define LRELU_SLOPE 0.01f

// ---------------- preprocessing ----------------

__global__ void k_degcount(const int* __restrict__ src, const int* __restrict__ dst,
                           int E, unsigned* __restrict__ dout_cnt, unsigned* __restrict__ din_cnt) {
    int e = blockIdx.x * blockDim.x + threadIdx.x;
    if (e < E) {
        atomicAdd(&dout_cnt[src[e]], 1u);
        atomicAdd(&din_cnt[dst[e]], 1u);
    }
}

__global__ void k_invsqrt(const unsigned* __restrict__ cnt, float* __restrict__ inv, int n) {
    int i = blockIdx.x * blockDim.x + threadIdx.x;
    if (i < n) {
        float d = fmaxf((float)cnt[i], 1.0f);
        inv[i] = 1.0f / sqrtf(d);
    }
}

// blocked Hillis-Steele inclusive scan, 256/block
__global__ void k_scan_block(const unsigned* __restrict__ in, unsigned* __restrict__ out,
                             unsigned* __restrict__ bsum, int n) {
    __shared__ unsigned s[256];
    int g = blockIdx.x * 256 + threadIdx.x;
    unsigned v = (g < n) ? in[g] : 0u;
    s[threadIdx.x] = v;
    __syncthreads();
    for (int off = 1; off < 256; off <<= 1) {
        unsigned t = (threadIdx.x >= (unsigned)off) ? s[threadIdx.x - off] : 0u;
        __syncthreads();
        s[threadIdx.x] += t;
        __syncthreads();
    }
    if (g < n) out[g] = s[threadIdx.x];
    if (threadIdx.x == 255) bsum[blockIdx.x] = s[255];
}

__global__ void k_scan_single(unsigned* __restrict__ bsum, int n) {
    __shared__ unsigned s[1024];
    int t = threadIdx.x;
    s[t] = (t < n) ? bsum[t] : 0u;
    __syncthreads();
    for (int off = 1; off < 1024; off <<= 1) {
        unsigned v = (t >= off) ? s[t - off] : 0u;
        __syncthreads();
        s[t] += v;
        __syncthreads();
    }
    if (t < n) bsum[t] = (t == 0) ? 0u : s[t - 1];
}

__global__ void k_finalize_rowptr(const unsigned* __restrict__ scanned, const unsigned* __restrict__ boff,
                                  unsigned* __restrict__ row_ptr, int n) {
    int g = blockIdx.x * blockDim.x + threadIdx.x;
    if (g < n) row_ptr[g + 1] = scanned[g] + boff[g >> 8];
    if (g == 0) row_ptr[0] = 0u;
}

__global__ void k_csr(const int* __restrict__ src, const int* __restrict__ dst, int E,
                      const unsigned* __restrict__ row_ptr, unsigned* __restrict__ cursor,
                      int* __restrict__ csr) {
    int e = blockIdx.x * blockDim.x + threadIdx.x;
    if (e < E) {
        int d = dst[e];
        unsigned slot = atomicAdd(&cursor[d], 1u);
        csr[row_ptr[d] + slot] = src[e];
    }
}

// ---------------- layer 1 (aggregate-first) ----------------

// pf4[i] = features[i] * dout_is[i]
__global__ void k_prescale4(const float* __restrict__ x, const float* __restrict__ dout_is,
                            float* __restrict__ pf4, int n) {
    int i = blockIdx.x * blockDim.x + threadIdx.x;
    if (i >= n) return;
    float s = dout_is[i];
    float4 v = *reinterpret_cast<const float4*>(x + (size_t)i * 4);
    float4 o = {v.x * s, v.y * s, v.z * s, v.w * s};
    *reinterpret_cast<float4*>(pf4 + (size_t)i * 4) = o;
}

// g[i] = din_is[i] * sum_{j->i} pf4[j]   (thread per node, 4-edge unroll)
__global__ void k_gather4(const float* __restrict__ pf4, const int* __restrict__ csr,
                          const unsigned* __restrict__ row_ptr, const float* __restrict__ din_is,
                          float* __restrict__ g, int n) {
    int i = blockIdx.x * blockDim.x + threadIdx.x;
    if (i >= n) return;
    unsigned beg = row_ptr[i], end = row_ptr[i + 1];
    float4 acc = {0.f, 0.f, 0.f, 0.f};
    unsigned e = beg;
    for (; e + 4 <= end; e += 4) {
        int s0 = csr[e], s1 = csr[e + 1], s2 = csr[e + 2], s3 = csr[e + 3];
        float4 v0 = *reinterpret_cast<const float4*>(pf4 + (size_t)s0 * 4);
        float4 v1 = *reinterpret_cast<const float4*>(pf4 + (size_t)s1 * 4);
        float4 v2 = *reinterpret_cast<const float4*>(pf4 + (size_t)s2 * 4);
        float4 v3 = *reinterpret_cast<const float4*>(pf4 + (size_t)s3 * 4);
        acc.x += (v0.x + v1.x) + (v2.x + v3.x);
        acc.y += (v0.y + v1.y) + (v2.y + v3.y);
        acc.z += (v0.z + v1.z) + (v2.z + v3.z);
        acc.w += (v0.w + v1.w) + (v2.w + v3.w);
    }
    for (; e < end; ++e) {
        int s = csr[e];
        float4 v = *reinterpret_cast<const float4*>(pf4 + (size_t)s * 4);
        acc.x += v.x; acc.y += v.y; acc.z += v.z; acc.w += v.w;
    }
    float di = din_is[i];
    float4 o = {acc.x * di, acc.y * di, acc.z * di, acc.w * di};
    *reinterpret_cast<float4*>(g + (size_t)i * 4) = o;
}

// out[i][j] = lrelu(g[i] . W1[:,j] + b1[j])
__global__ void k_lin1b(const float* __restrict__ g, const float* __restrict__ W,
                        const float* __restrict__ b, float* __restrict__ out, int n) {
    int t = blockIdx.x * blockDim.x + threadIdx.x;
    int i = t >> 7, j = t & 127;
    if (i >= n) return;
    float4 gv = *reinterpret_cast<const float4*>(g + (size_t)i * 4);
    float acc = gv.x * W[0 * 128 + j] + gv.y * W[1 * 128 + j] + gv.z * W[2 * 128 + j] + gv.w * W[3 * 128 + j];
    float v = acc + b[j];
    out[(size_t)i * 128 + j] = (v >= 0.f) ? v : LRELU_SLOPE * v;
}

// ---------------- middle layers ----------------

// h[i] = (x[i] @ W) * dout_is[i].  No LDS: W (64KB) is L1/L2-hot.
// 256 threads = 2 groups x 128 j-lanes; each group register-blocks 8 nodes.
__global__ __launch_bounds__(256) void k_lin128(const float* __restrict__ x, const float* __restrict__ W,
                                                const float* __restrict__ dout_is, float* __restrict__ h, int n) {
    int j = threadIdx.x & 127;
    int grp = threadIdx.x >> 7;  // 0..1
    int i0 = blockIdx.x * 16 + grp * 8;
    if (i0 >= n) return;
    if (i0 + 8 <= n) {
        const float* xp = x + (size_t)i0 * 128;
        float acc0 = 0.f, acc1 = 0.f, acc2 = 0.f, acc3 = 0.f;
        float acc4 = 0.f, acc5 = 0.f, acc6 = 0.f, acc7 = 0.f;
#pragma unroll 2
        for (int k = 0; k < 128; k += 4) {
            float w0 = W[(k + 0) * 128 + j];
            float w1 = W[(k + 1) * 128 + j];
            float w2 = W[(k + 2) * 128 + j];
            float w3 = W[(k + 3) * 128 + j];
            float4 a0 = *reinterpret_cast<const float4*>(xp + 0 * 128 + k);
            float4 a1 = *reinterpret_cast<const float4*>(xp + 1 * 128 + k);
            float4 a2 = *reinterpret_cast<const float4*>(xp + 2 * 128 + k);
            float4 a3 = *reinterpret_cast<const float4*>(xp + 3 * 128 + k);
            float4 a4 = *reinterpret_cast<const float4*>(xp + 4 * 128 + k);
            float4 a5 = *reinterpret_cast<const float4*>(xp + 5 * 128 + k);
            float4 a6 = *reinterpret_cast<const float4*>(xp + 6 * 128 + k);
            float4 a7 = *reinterpret_cast<const float4*>(xp + 7 * 128 + k);
            acc0 += a0.x * w0 + a0.y * w1 + a0.z * w2 + a0.w * w3;
            acc1 += a1.x * w0 + a1.y * w1 + a1.z * w2 + a1.w * w3;
            acc2 += a2.x * w0 + a2.y * w1 + a2.z * w2 + a2.w * w3;
            acc3 += a3.x * w0 + a3.y * w1 + a3.z * w2 + a3.w * w3;
            acc4 += a4.x * w0 + a4.y * w1 + a4.z * w2 + a4.w * w3;
            acc5 += a5.x * w0 + a5.y * w1 + a5.z * w2 + a5.w * w3;
            acc6 += a6.x * w0 + a6.y * w1 + a6.z * w2 + a6.w * w3;
            acc7 += a7.x * w0 + a7.y * w1 + a7.z * w2 + a7.w * w3;
        }
        h[(size_t)(i0 + 0) * 128 + j] = acc0 * dout_is[i0 + 0];
        h[(size_t)(i0 + 1) * 128 + j] = acc1 * dout_is[i0 + 1];
        h[(size_t)(i0 + 2) * 128 + j] = acc2 * dout_is[i0 + 2];
        h[(size_t)(i0 + 3) * 128 + j] = acc3 * dout_is[i0 + 3];
        h[(size_t)(i0 + 4) * 128 + j] = acc4 * dout_is[i0 + 4];
        h[(size_t)(i0 + 5) * 128 + j] = acc5 * dout_is[i0 + 5];
        h[(size_t)(i0 + 6) * 128 + j] = acc6 * dout_is[i0 + 6];
        h[(size_t)(i0 + 7) * 128 + j] = acc7 * dout_is[i0 + 7];
    } else {
        for (int i = i0; i < n; ++i) {
            const float* xr = x + (size_t)i * 128;
            float acc = 0.f;
            for (int k = 0; k < 128; ++k) acc += xr[k] * W[k * 128 + j];
            h[(size_t)i * 128 + j] = acc * dout_is[i];
        }
    }
}

// gather + din_is*acc + b (+ lrelu). 8 nodes/block, 32 lanes/node, float4.
__global__ __launch_bounds__(256) void k_gather128v(const float* __restrict__ h, const int* __restrict__ csr,
                                                    const unsigned* __restrict__ row_ptr,
                                                    const float* __restrict__ din_is, const float* __restrict__ b,
                                                    float* __restrict__ xo, int n, int relu) {
    int node = blockIdx.x * 8 + (threadIdx.x >> 5);
    if (node >= n) return;
    int j4 = (threadIdx.x & 31) * 4;
    unsigned beg = row_ptr[node], end = row_ptr[node + 1];
    float4 acc = {0.f, 0.f, 0.f, 0.f};
    unsigned e = beg;
    for (; e + 4 <= end; e += 4) {
        int s0 = csr[e], s1 = csr[e + 1], s2 = csr[e + 2], s3 = csr[e + 3];
        float4 v0 = *reinterpret_cast<const float4*>(h + (size_t)s0 * 128 + j4);
        float4 v1 = *reinterpret_cast<const float4*>(h + (size_t)s1 * 128 + j4);
        float4 v2 = *reinterpret_cast<const float4*>(h + (size_t)s2 * 128 + j4);
        float4 v3 = *reinterpret_cast<const float4*>(h + (size_t)s3 * 128 + j4);
        acc.x += (v0.x + v1.x) + (v2.x + v3.x);
        acc.y += (v0.y + v1.y) + (v2.y + v3.y);
        acc.z += (v0.z + v1.z) + (v2.z + v3.z);
        acc.w += (v0.w + v1.w) + (v2.w + v3.w);
    }
    for (; e < end; ++e) {
        int s = csr[e];
        float4 v = *reinterpret_cast<const float4*>(h + (size_t)s * 128 + j4);
        acc.x += v.x; acc.y += v.y; acc.z += v.z; acc.w += v.w;
    }
    float di = din_is[node];
    float4 bb = *reinterpret_cast<const float4*>(b + j4);
    float4 o = {acc.x * di + bb.x, acc.y * di + bb.y, acc.z * di + bb.z, acc.w * di + bb.w};
    if (relu) {
        o.x = (o.x >= 0.f) ? o.x : LRELU_SLOPE * o.x;
        o.y = (o.y >= 0.f) ? o.y : LRELU_SLOPE * o.y;
        o.z = (o.z >= 0.f) ? o.z : LRELU_SLOPE * o.z;
        o.w = (o.w >= 0.f) ? o.w : LRELU_SLOPE * o.w;
    }
    *reinterpret_cast<float4*>(xo + (size_t)node * 128 + j4) = o;
}

// ---------------- layer 5 ----------------

// h[i][0..2] = (x[i]*dout_is[i]) @ W5.  8 nodes/block, 32 lanes/node.
__global__ __launch_bounds__(256) void k_lin5v(const float* __restrict__ x, const float* __restrict__ W,
                                               const float* __restrict__ dout_is, float* __restrict__ h, int n) {
    int node = blockIdx.x * 8 + (threadIdx.x >> 5);
    if (node >= n) return;
    int l = threadIdx.x & 31;
    int k4 = l * 4;
    float s = dout_is[node];
    float4 xv = *reinterpret_cast<const float4*>(x + (size_t)node * 128 + k4);
    xv.x *= s; xv.y *= s; xv.z *= s; xv.w *= s;
    // W5 row-major [128][3]; lane covers rows k4..k4+3 -> 12 contiguous floats
    float4 wA = *reinterpret_cast<const float4*>(W + (size_t)k4 * 3);
    float4 wB = *reinterpret_cast<const float4*>(W + (size_t)k4 * 3 + 4);
    float4 wC = *reinterpret_cast<const float4*>(W + (size_t)k4 * 3 + 8);
    // rows: k4:(wA.x,wA.y,wA.z) k4+1:(wA.w,wB.x,wB.y) k4+2:(wB.z,wB.w,wC.x) k4+3:(wC.y,wC.z,wC.w)
    float p0 = xv.x * wA.x + xv.y * wA.w + xv.z * wB.z + xv.w * wC.y;
    float p1 = xv.x * wA.y + xv.y * wB.x + xv.z * wB.w + xv.w * wC.z;
    float p2 = xv.x * wA.z + xv.y * wB.y + xv.z * wC.x + xv.w * wC.w;
    for (int off = 16; off; off >>= 1) {
        p0 += __shfl_xor(p0, off, 32);
        p1 += __shfl_xor(p1, off, 32);
        p2 += __shfl_xor(p2, off, 32);
    }
    if (l == 0) {
        h[(size_t)node * 3 + 0] = p0;
        h[(size_t)node * 3 + 1] = p1;
        h[(size_t)node * 3 + 2] = p2;
    }
}

__global__ void k_gather3(const float* __restrict__ h, const int* __restrict__ csr,
                          const unsigned* __restrict__ row_ptr, const float* __restrict__ din_is,
                          const float* __restrict__ b, float* __restrict__ out, int n) {
    int i = blockIdx.x * blockDim.x + threadIdx.x;
    if (i >= n) return;
    unsigned beg = row_ptr[i], end = row_ptr[i + 1];
    float a0 = 0.f, a1 = 0.f, a2 = 0.f;
    for (unsigned e = beg; e < end; ++e) {
        int s = csr[e];
        a0 += h[(size_t)s * 3 + 0];
        a1 += h[(size_t)s * 3 + 1];
        a2 += h[(size_t)s * 3 + 2];
    }
    float di = din_is[i];
    out[(size_t)i * 3 + 0] = a0 * di + b[0];
    out[(size_t)i * 3 + 1] = a1 * di + b[1];
    out[(size_t)i * 3 + 2] = a2 * di + b[2];
}

// ---------------- launch ----------------

extern "C" void kernel_launch(void* const* d_in, const int* in_sizes, int n_in,
                              void* d_out, int out_size, void* d_ws, size_t ws_size,
                              hipStream_t stream) {
    const float* features = (const float*)d_in[0];
    const int* esrc = (const int*)d_in[1];
    const int* edst = (const int*)d_in[2];
    const float* W1 = (const float*)d_in[3];  const float* b1 = (const float*)d_in[4];
    const float* W2 = (const float*)d_in[5];  const float* b2 = (const float*)d_in[6];
    const float* W3 = (const float*)d_in[7];  const float* b3 = (const float*)d_in[8];
    const float* W4 = (const float*)d_in[9];  const float* b4 = (const float*)d_in[10];
    const float* W5 = (const float*)d_in[11]; const float* b5 = (const float*)d_in[12];

    const int N = in_sizes[0] / 4;
    const int E = in_sizes[1];

    size_t off = 0;
    auto carve = [&](size_t bytes) -> void* {
        void* p = (char*)d_ws + off;
        off = (off + bytes + 255) & ~(size_t)255;
        return p;
    };
    float*    A        = (float*)carve((size_t)N * 128 * 4);
    float*    B        = (float*)carve((size_t)N * 128 * 4);
    int*      csr      = (int*)carve((size_t)E * 4);
    unsigned* row_ptr  = (unsigned*)carve((size_t)(N + 1) * 4);
    unsigned* cursor   = (unsigned*)carve((size_t)N * 4);
    unsigned* dout_cnt = (unsigned*)carve((size_t)N * 4);
    unsigned* din_cnt  = (unsigned*)carve((size_t)N * 4);
    float*    dout_is  = (float*)carve((size_t)N * 4);
    float*    din_is   = (float*)carve((size_t)N * 4);
    unsigned* scan_tmp = (unsigned*)carve((size_t)N * 4);
    unsigned* bsum     = (unsigned*)carve(4096);
    (void)ws_size;
    // small per-layer-1 buffers alias the (not yet used) B buffer
    float* pf4 = B;                       // N*4 floats
    float* g4  = B + (size_t)N * 4;       // N*4 floats

    hipMemsetAsync(dout_cnt, 0, (size_t)N * 4, stream);
    hipMemsetAsync(din_cnt, 0, (size_t)N * 4, stream);
    hipMemsetAsync(cursor, 0, (size_t)N * 4, stream);

    k_degcount<<<(E + 255) / 256, 256, 0, stream>>>(esrc, edst, E, dout_cnt, din_cnt);
    k_invsqrt<<<(N + 255) / 256, 256, 0, stream>>>(dout_cnt, dout_is, N);
    k_invsqrt<<<(N + 255) / 256, 256, 0, stream>>>(din_cnt, din_is, N);

    int nscan = (N + 255) / 256;
    k_scan_block<<<nscan, 256, 0, stream>>>(din_cnt, scan_tmp, bsum, N);
    k_scan_single<<<1, 1024, 0, stream>>>(bsum, nscan);
    k_finalize_rowptr<<<(N + 255) / 256, 256, 0, stream>>>(scan_tmp, bsum, row_ptr, N);
    k_csr<<<(E + 255) / 256, 256, 0, stream>>>(esrc, edst, E, row_ptr, cursor, csr);

    // layer 1: aggregate 4-wide first, then 4->128 GEMM (+bias+lrelu)
    k_prescale4<<<(N + 255) / 256, 256, 0, stream>>>(features, dout_is, pf4, N);
    k_gather4<<<(N + 255) / 256, 256, 0, stream>>>(pf4, csr, row_ptr, din_is, g4, N);
    k_lin1b<<<((size_t)N * 128 + 255) / 256, 256, 0, stream>>>(g4, W1, b1, A, N);

    // layers 2-4: 128 -> 128
    k_lin128<<<(N + 15) / 16, 256, 0, stream>>>(A, W2, dout_is, B, N);
    k_gather128v<<<(N + 7) / 8, 256, 0, stream>>>(B, csr, row_ptr, din_is, b2, A, N, 1);
    k_lin128<<<(N + 15) / 16, 256, 0, stream>>>(A, W3, dout_is, B, N);
    k_gather128v<<<(N + 7) / 8, 256, 0, stream>>>(B, csr, row_ptr, din_is, b3, A, N, 1);
    k_lin128<<<(N + 15) / 16, 256, 0, stream>>>(A, W4, dout_is, B, N);
    k_gather128v<<<(N + 7) / 8, 256, 0, stream>>>(B, csr, row_ptr, din_is, b4, A, N, 1);

    // layer 5: 128 -> 3, then 3-wide gather
    k_lin5v<<<(N + 7) / 8, 256, 0, stream>>>(A, W5, dout_is, B, N);
    k_gather3<<<(N + 255) / 256, 256, 0, stream>>>(B, csr, row_ptr, din_is, b5, (float*)d_out, N);
}

// Round 3
// 810.048 us; speedup vs baseline: 1.9257x; 1.5526x over previous
//
#include <hip/hip_runtime.h>
#include <math.h>

// GraphConv x5 (DGL norm='both') on MI355X.
// Layer 1 aggregates 4-wide features first (algebra: agg commutes with W).
// Layers 2-4: lin128 (lane=node, 16-j tile, W via scalar loads, x in LDS),
// then float4 gather fused with din_is*acc+b+leakyrelu.
// Layer 5: 128->3 GEMM then 3-wide gather.

#define LRELU_SLOPE 0.01f

// ---------------- preprocessing ----------------

__global__ void k_degcount(const int* __restrict__ src, const int* __restrict__ dst,
                           int E, unsigned* __restrict__ dout_cnt, unsigned* __restrict__ din_cnt) {
    int e = blockIdx.x * blockDim.x + threadIdx.x;
    if (e < E) {
        atomicAdd(&dout_cnt[src[e]], 1u);
        atomicAdd(&din_cnt[dst[e]], 1u);
    }
}

__global__ void k_invsqrt(const unsigned* __restrict__ cnt, float* __restrict__ inv, int n) {
    int i = blockIdx.x * blockDim.x + threadIdx.x;
    if (i < n) {
        float d = fmaxf((float)cnt[i], 1.0f);
        inv[i] = 1.0f / sqrtf(d);
    }
}

// blocked Hillis-Steele inclusive scan, 256/block
__global__ void k_scan_block(const unsigned* __restrict__ in, unsigned* __restrict__ out,
                             unsigned* __restrict__ bsum, int n) {
    __shared__ unsigned s[256];
    int g = blockIdx.x * 256 + threadIdx.x;
    unsigned v = (g < n) ? in[g] : 0u;
    s[threadIdx.x] = v;
    __syncthreads();
    for (int off = 1; off < 256; off <<= 1) {
        unsigned t = (threadIdx.x >= (unsigned)off) ? s[threadIdx.x - off] : 0u;
        __syncthreads();
        s[threadIdx.x] += t;
        __syncthreads();
    }
    if (g < n) out[g] = s[threadIdx.x];
    if (threadIdx.x == 255) bsum[blockIdx.x] = s[255];
}

__global__ void k_scan_single(unsigned* __restrict__ bsum, int n) {
    __shared__ unsigned s[1024];
    int t = threadIdx.x;
    s[t] = (t < n) ? bsum[t] : 0u;
    __syncthreads();
    for (int off = 1; off < 1024; off <<= 1) {
        unsigned v = (t >= off) ? s[t - off] : 0u;
        __syncthreads();
        s[t] += v;
        __syncthreads();
    }
    if (t < n) bsum[t] = (t == 0) ? 0u : s[t - 1];
}

__global__ void k_finalize_rowptr(const unsigned* __restrict__ scanned, const unsigned* __restrict__ boff,
                                  unsigned* __restrict__ row_ptr, int n) {
    int g = blockIdx.x * blockDim.x + threadIdx.x;
    if (g < n) row_ptr[g + 1] = scanned[g] + boff[g >> 8];
    if (g == 0) row_ptr[0] = 0u;
}

__global__ void k_csr(const int* __restrict__ src, const int* __restrict__ dst, int E,
                      const unsigned* __restrict__ row_ptr, unsigned* __restrict__ cursor,
                      int* __restrict__ csr) {
    int e = blockIdx.x * blockDim.x + threadIdx.x;
    if (e < E) {
        int d = dst[e];
        unsigned slot = atomicAdd(&cursor[d], 1u);
        csr[row_ptr[d] + slot] = src[e];
    }
}

// ---------------- layer 1 (aggregate-first) ----------------

__global__ void k_prescale4(const float* __restrict__ x, const float* __restrict__ dout_is,
                            float* __restrict__ pf4, int n) {
    int i = blockIdx.x * blockDim.x + threadIdx.x;
    if (i >= n) return;
    float s = dout_is[i];
    float4 v = *reinterpret_cast<const float4*>(x + (size_t)i * 4);
    float4 o = {v.x * s, v.y * s, v.z * s, v.w * s};
    *reinterpret_cast<float4*>(pf4 + (size_t)i * 4) = o;
}

__global__ void k_gather4(const float* __restrict__ pf4, const int* __restrict__ csr,
                          const unsigned* __restrict__ row_ptr, const float* __restrict__ din_is,
                          float* __restrict__ g, int n) {
    int i = blockIdx.x * blockDim.x + threadIdx.x;
    if (i >= n) return;
    unsigned beg = row_ptr[i], end = row_ptr[i + 1];
    float4 acc = {0.f, 0.f, 0.f, 0.f};
    unsigned e = beg;
    for (; e + 4 <= end; e += 4) {
        int s0 = csr[e], s1 = csr[e + 1], s2 = csr[e + 2], s3 = csr[e + 3];
        float4 v0 = *reinterpret_cast<const float4*>(pf4 + (size_t)s0 * 4);
        float4 v1 = *reinterpret_cast<const float4*>(pf4 + (size_t)s1 * 4);
        float4 v2 = *reinterpret_cast<const float4*>(pf4 + (size_t)s2 * 4);
        float4 v3 = *reinterpret_cast<const float4*>(pf4 + (size_t)s3 * 4);
        acc.x += (v0.x + v1.x) + (v2.x + v3.x);
        acc.y += (v0.y + v1.y) + (v2.y + v3.y);
        acc.z += (v0.z + v1.z) + (v2.z + v3.z);
        acc.w += (v0.w + v1.w) + (v2.w + v3.w);
    }
    for (; e < end; ++e) {
        int s = csr[e];
        float4 v = *reinterpret_cast<const float4*>(pf4 + (size_t)s * 4);
        acc.x += v.x; acc.y += v.y; acc.z += v.z; acc.w += v.w;
    }
    float di = din_is[i];
    float4 o = {acc.x * di, acc.y * di, acc.z * di, acc.w * di};
    *reinterpret_cast<float4*>(g + (size_t)i * 4) = o;
}

__global__ void k_lin1b(const float* __restrict__ g, const float* __restrict__ W,
                        const float* __restrict__ b, float* __restrict__ out, int n) {
    int t = blockIdx.x * blockDim.x + threadIdx.x;
    int i = t >> 7, j = t & 127;
    if (i >= n) return;
    float4 gv = *reinterpret_cast<const float4*>(g + (size_t)i * 4);
    float acc = gv.x * W[0 * 128 + j] + gv.y * W[1 * 128 + j] + gv.z * W[2 * 128 + j] + gv.w * W[3 * 128 + j];
    float v = acc + b[j];
    out[(size_t)i * 128 + j] = (v >= 0.f) ? v : LRELU_SLOPE * v;
}

// ---------------- middle layers ----------------

// h[i] = (x[i] @ W) * dout_is[i].
// lane = node (64 nodes/block), 8 waves each own a 16-wide j-tile.
// x staged in LDS [64][129] (pad -> bank (lane+k)%32, 2-way = free).
// W addresses are wave-uniform (readfirstlane) -> scalar s_loads, SGPR
// operands feed v_fma directly. 64 FMA-insts per 4 ds_read_b32 per k4.
#define XPAD 129
__global__ __launch_bounds__(512) void k_lin128(const float* __restrict__ x, const float* __restrict__ W,
                                                const float* __restrict__ dout_is, float* __restrict__ h, int n) {
    __shared__ float xs[64 * XPAD];  // 33 KB
    const int t = threadIdx.x;
    const int bbase = blockIdx.x * 64;
    // stage x[bbase .. bbase+63][0..127] into LDS, coalesced float4 reads
#pragma unroll
    for (int r = 0; r < 4; ++r) {
        int f4 = t + r * 512;            // 0..2047
        int row = f4 >> 5;
        int c4 = (f4 & 31) << 2;
        int gn = bbase + row;
        float4 v = {0.f, 0.f, 0.f, 0.f};
        if (gn < n) v = *reinterpret_cast<const float4*>(x + (size_t)gn * 128 + c4);
        float* d = xs + row * XPAD + c4;
        d[0] = v.x; d[1] = v.y; d[2] = v.z; d[3] = v.w;
    }
    __syncthreads();

    const int lane = t & 63;
    const int jg = __builtin_amdgcn_readfirstlane(t >> 6) & 7;  // wave-uniform 0..7
    const int j0 = jg * 16;
    const float* Wj = W + j0;
    const float* xrow = xs + lane * XPAD;

    float acc[16];
#pragma unroll
    for (int q = 0; q < 16; ++q) acc[q] = 0.f;

#pragma unroll 2
    for (int k = 0; k < 128; k += 4) {
        float x0 = xrow[k + 0];
        float x1 = xrow[k + 1];
        float x2 = xrow[k + 2];
        float x3 = xrow[k + 3];
        const float* w0 = Wj + (size_t)k * 128;
#pragma unroll
        for (int q = 0; q < 16; ++q) {
            acc[q] += x0 * w0[q] + x1 * w0[128 + q] + x2 * w0[256 + q] + x3 * w0[384 + q];
        }
    }

    int node = bbase + lane;
    if (node < n) {
        float s = dout_is[node];
        float* out = h + (size_t)node * 128 + j0;
#pragma unroll
        for (int q = 0; q < 16; q += 4) {
            float4 o = {acc[q] * s, acc[q + 1] * s, acc[q + 2] * s, acc[q + 3] * s};
            *reinterpret_cast<float4*>(out + q) = o;
        }
    }
}

// gather + din_is*acc + b (+ lrelu). 8 nodes/block, 32 lanes/node, float4.
__global__ __launch_bounds__(256) void k_gather128v(const float* __restrict__ h, const int* __restrict__ csr,
                                                    const unsigned* __restrict__ row_ptr,
                                                    const float* __restrict__ din_is, const float* __restrict__ b,
                                                    float* __restrict__ xo, int n, int relu) {
    int node = blockIdx.x * 8 + (threadIdx.x >> 5);
    if (node >= n) return;
    int j4 = (threadIdx.x & 31) * 4;
    unsigned beg = row_ptr[node], end = row_ptr[node + 1];
    float4 acc = {0.f, 0.f, 0.f, 0.f};
    unsigned e = beg;
    for (; e + 4 <= end; e += 4) {
        int s0 = csr[e], s1 = csr[e + 1], s2 = csr[e + 2], s3 = csr[e + 3];
        float4 v0 = *reinterpret_cast<const float4*>(h + (size_t)s0 * 128 + j4);
        float4 v1 = *reinterpret_cast<const float4*>(h + (size_t)s1 * 128 + j4);
        float4 v2 = *reinterpret_cast<const float4*>(h + (size_t)s2 * 128 + j4);
        float4 v3 = *reinterpret_cast<const float4*>(h + (size_t)s3 * 128 + j4);
        acc.x += (v0.x + v1.x) + (v2.x + v3.x);
        acc.y += (v0.y + v1.y) + (v2.y + v3.y);
        acc.z += (v0.z + v1.z) + (v2.z + v3.z);
        acc.w += (v0.w + v1.w) + (v2.w + v3.w);
    }
    for (; e < end; ++e) {
        int s = csr[e];
        float4 v = *reinterpret_cast<const float4*>(h + (size_t)s * 128 + j4);
        acc.x += v.x; acc.y += v.y; acc.z += v.z; acc.w += v.w;
    }
    float di = din_is[node];
    float4 bb = *reinterpret_cast<const float4*>(b + j4);
    float4 o = {acc.x * di + bb.x, acc.y * di + bb.y, acc.z * di + bb.z, acc.w * di + bb.w};
    if (relu) {
        o.x = (o.x >= 0.f) ? o.x : LRELU_SLOPE * o.x;
        o.y = (o.y >= 0.f) ? o.y : LRELU_SLOPE * o.y;
        o.z = (o.z >= 0.f) ? o.z : LRELU_SLOPE * o.z;
        o.w = (o.w >= 0.f) ? o.w : LRELU_SLOPE * o.w;
    }
    *reinterpret_cast<float4*>(xo + (size_t)node * 128 + j4) = o;
}

// ---------------- layer 5 ----------------

__global__ __launch_bounds__(256) void k_lin5v(const float* __restrict__ x, const float* __restrict__ W,
                                               const float* __restrict__ dout_is, float* __restrict__ h, int n) {
    int node = blockIdx.x * 8 + (threadIdx.x >> 5);
    if (node >= n) return;
    int l = threadIdx.x & 31;
    int k4 = l * 4;
    float s = dout_is[node];
    float4 xv = *reinterpret_cast<const float4*>(x + (size_t)node * 128 + k4);
    xv.x *= s; xv.y *= s; xv.z *= s; xv.w *= s;
    float4 wA = *reinterpret_cast<const float4*>(W + (size_t)k4 * 3);
    float4 wB = *reinterpret_cast<const float4*>(W + (size_t)k4 * 3 + 4);
    float4 wC = *reinterpret_cast<const float4*>(W + (size_t)k4 * 3 + 8);
    float p0 = xv.x * wA.x + xv.y * wA.w + xv.z * wB.z + xv.w * wC.y;
    float p1 = xv.x * wA.y + xv.y * wB.x + xv.z * wB.w + xv.w * wC.z;
    float p2 = xv.x * wA.z + xv.y * wB.y + xv.z * wC.x + xv.w * wC.w;
    for (int off = 16; off; off >>= 1) {
        p0 += __shfl_xor(p0, off, 32);
        p1 += __shfl_xor(p1, off, 32);
        p2 += __shfl_xor(p2, off, 32);
    }
    if (l == 0) {
        h[(size_t)node * 3 + 0] = p0;
        h[(size_t)node * 3 + 1] = p1;
        h[(size_t)node * 3 + 2] = p2;
    }
}

__global__ void k_gather3(const float* __restrict__ h, const int* __restrict__ csr,
                          const unsigned* __restrict__ row_ptr, const float* __restrict__ din_is,
                          const float* __restrict__ b, float* __restrict__ out, int n) {
    int i = blockIdx.x * blockDim.x + threadIdx.x;
    if (i >= n) return;
    unsigned beg = row_ptr[i], end = row_ptr[i + 1];
    float a0 = 0.f, a1 = 0.f, a2 = 0.f;
    for (unsigned e = beg; e < end; ++e) {
        int s = csr[e];
        a0 += h[(size_t)s * 3 + 0];
        a1 += h[(size_t)s * 3 + 1];
        a2 += h[(size_t)s * 3 + 2];
    }
    float di = din_is[i];
    out[(size_t)i * 3 + 0] = a0 * di + b[0];
    out[(size_t)i * 3 + 1] = a1 * di + b[1];
    out[(size_t)i * 3 + 2] = a2 * di + b[2];
}

// ---------------- launch ----------------

extern "C" void kernel_launch(void* const* d_in, const int* in_sizes, int n_in,
                              void* d_out, int out_size, void* d_ws, size_t ws_size,
                              hipStream_t stream) {
    const float* features = (const float*)d_in[0];
    const int* esrc = (const int*)d_in[1];
    const int* edst = (const int*)d_in[2];
    const float* W1 = (const float*)d_in[3];  const float* b1 = (const float*)d_in[4];
    const float* W2 = (const float*)d_in[5];  const float* b2 = (const float*)d_in[6];
    const float* W3 = (const float*)d_in[7];  const float* b3 = (const float*)d_in[8];
    const float* W4 = (const float*)d_in[9];  const float* b4 = (const float*)d_in[10];
    const float* W5 = (const float*)d_in[11]; const float* b5 = (const float*)d_in[12];

    const int N = in_sizes[0] / 4;
    const int E = in_sizes[1];

    size_t off = 0;
    auto carve = [&](size_t bytes) -> void* {
        void* p = (char*)d_ws + off;
        off = (off + bytes + 255) & ~(size_t)255;
        return p;
    };
    float*    A        = (float*)carve((size_t)N * 128 * 4);
    float*    B        = (float*)carve((size_t)N * 128 * 4);
    int*      csr      = (int*)carve((size_t)E * 4);
    unsigned* row_ptr  = (unsigned*)carve((size_t)(N + 1) * 4);
    unsigned* cursor   = (unsigned*)carve((size_t)N * 4);
    unsigned* dout_cnt = (unsigned*)carve((size_t)N * 4);
    unsigned* din_cnt  = (unsigned*)carve((size_t)N * 4);
    float*    dout_is  = (float*)carve((size_t)N * 4);
    float*    din_is   = (float*)carve((size_t)N * 4);
    unsigned* scan_tmp = (unsigned*)carve((size_t)N * 4);
    unsigned* bsum     = (unsigned*)carve(4096);
    (void)ws_size;
    float* pf4 = B;                       // N*4 floats (aliases B, free now)
    float* g4  = B + (size_t)N * 4;       // N*4 floats

    hipMemsetAsync(dout_cnt, 0, (size_t)N * 4, stream);
    hipMemsetAsync(din_cnt, 0, (size_t)N * 4, stream);
    hipMemsetAsync(cursor, 0, (size_t)N * 4, stream);

    k_degcount<<<(E + 255) / 256, 256, 0, stream>>>(esrc, edst, E, dout_cnt, din_cnt);
    k_invsqrt<<<(N + 255) / 256, 256, 0, stream>>>(dout_cnt, dout_is, N);
    k_invsqrt<<<(N + 255) / 256, 256, 0, stream>>>(din_cnt, din_is, N);

    int nscan = (N + 255) / 256;
    k_scan_block<<<nscan, 256, 0, stream>>>(din_cnt, scan_tmp, bsum, N);
    k_scan_single<<<1, 1024, 0, stream>>>(bsum, nscan);
    k_finalize_rowptr<<<(N + 255) / 256, 256, 0, stream>>>(scan_tmp, bsum, row_ptr, N);
    k_csr<<<(E + 255) / 256, 256, 0, stream>>>(esrc, edst, E, row_ptr, cursor, csr);

    // layer 1: aggregate 4-wide first, then 4->128 GEMM (+bias+lrelu)
    k_prescale4<<<(N + 255) / 256, 256, 0, stream>>>(features, dout_is, pf4, N);
    k_gather4<<<(N + 255) / 256, 256, 0, stream>>>(pf4, csr, row_ptr, din_is, g4, N);
    k_lin1b<<<((size_t)N * 128 + 255) / 256, 256, 0, stream>>>(g4, W1, b1, A, N);

    // layers 2-4: 128 -> 128
    int linGrid = (N + 63) / 64;
    k_lin128<<<linGrid, 512, 0, stream>>>(A, W2, dout_is, B, N);
    k_gather128v<<<(N + 7) / 8, 256, 0, stream>>>(B, csr, row_ptr, din_is, b2, A, N, 1);
    k_lin128<<<linGrid, 512, 0, stream>>>(A, W3, dout_is, B, N);
    k_gather128v<<<(N + 7) / 8, 256, 0, stream>>>(B, csr, row_ptr, din_is, b3, A, N, 1);
    k_lin128<<<linGrid, 512, 0, stream>>>(A, W4, dout_is, B, N);
    k_gather128v<<<(N + 7) / 8, 256, 0, stream>>>(B, csr, row_ptr, din_is, b4, A, N, 1);

    // layer 5: 128 -> 3, then 3-wide gather
    k_lin5v<<<(N + 7) / 8, 256, 0, stream>>>(A, W5, dout_is, B, N);
    k_gather3<<<(N + 255) / 256, 256, 0, stream>>>(B, csr, row_ptr, din_is, b5, (float*)d_out, N);
}

// Round 4
// 751.299 us; speedup vs baseline: 2.0763x; 1.0782x over previous
//
#include <hip/hip_runtime.h>
#include <math.h>

// GraphConv x5 (DGL norm='both') on MI355X.
// xp-layer invariant: each layer's epilogue writes xp = dout_is * lrelu(y),
// i.e. the *prescaled* input of the next layer. Middle layers are fully
// fused: gather(xp)->LDS tile -> GEMM(W)+b+lrelu+prescale -> xp_next.
// CSR built with ONE atomic pass: rank[e] = atomicAdd(din_cnt[dst])'s old
// value gives each edge its slot; scatter pass is atomic-free.

#define LRELU_SLOPE 0.01f
#define XPAD 129  // 128+1: LDS bank (lane+k)%32 -> 2-way on wave64 = free

// ---------------- preprocessing ----------------

__global__ void k_degcount_rank(const int* __restrict__ src, const int* __restrict__ dst,
                                int E, unsigned* __restrict__ dout_cnt,
                                unsigned* __restrict__ din_cnt, unsigned* __restrict__ rank) {
    int e = blockIdx.x * blockDim.x + threadIdx.x;
    if (e < E) {
        atomicAdd(&dout_cnt[src[e]], 1u);
        rank[e] = atomicAdd(&din_cnt[dst[e]], 1u);
    }
}

__global__ void k_invsqrt2(const unsigned* __restrict__ c0, float* __restrict__ i0,
                           const unsigned* __restrict__ c1, float* __restrict__ i1, int n) {
    int i = blockIdx.x * blockDim.x + threadIdx.x;
    if (i < n) {
        i0[i] = 1.0f / sqrtf(fmaxf((float)c0[i], 1.0f));
        i1[i] = 1.0f / sqrtf(fmaxf((float)c1[i], 1.0f));
    }
}

// blocked Hillis-Steele inclusive scan, 256/block
__global__ void k_scan_block(const unsigned* __restrict__ in, unsigned* __restrict__ out,
                             unsigned* __restrict__ bsum, int n) {
    __shared__ unsigned s[256];
    int g = blockIdx.x * 256 + threadIdx.x;
    unsigned v = (g < n) ? in[g] : 0u;
    s[threadIdx.x] = v;
    __syncthreads();
    for (int off = 1; off < 256; off <<= 1) {
        unsigned t = (threadIdx.x >= (unsigned)off) ? s[threadIdx.x - off] : 0u;
        __syncthreads();
        s[threadIdx.x] += t;
        __syncthreads();
    }
    if (g < n) out[g] = s[threadIdx.x];
    if (threadIdx.x == 255) bsum[blockIdx.x] = s[255];
}

__global__ void k_scan_single(unsigned* __restrict__ bsum, int n) {
    __shared__ unsigned s[1024];
    int t = threadIdx.x;
    s[t] = (t < n) ? bsum[t] : 0u;
    __syncthreads();
    for (int off = 1; off < 1024; off <<= 1) {
        unsigned v = (t >= off) ? s[t - off] : 0u;
        __syncthreads();
        s[t] += v;
        __syncthreads();
    }
    if (t < n) bsum[t] = (t == 0) ? 0u : s[t - 1];
}

__global__ void k_finalize_rowptr(const unsigned* __restrict__ scanned, const unsigned* __restrict__ boff,
                                  unsigned* __restrict__ row_ptr, int n) {
    int g = blockIdx.x * blockDim.x + threadIdx.x;
    if (g < n) row_ptr[g + 1] = scanned[g] + boff[g >> 8];
    if (g == 0) row_ptr[0] = 0u;
}

// atomic-free CSR fill using precomputed per-edge rank
__global__ void k_csr_scatter(const int* __restrict__ src, const int* __restrict__ dst, int E,
                              const unsigned* __restrict__ row_ptr, const unsigned* __restrict__ rank,
                              int* __restrict__ csr) {
    int e = blockIdx.x * blockDim.x + threadIdx.x;
    if (e < E) csr[row_ptr[dst[e]] + rank[e]] = src[e];
}

// ---------------- layer 1 (aggregate-first, 4-wide) ----------------

__global__ void k_prescale4(const float* __restrict__ x, const float* __restrict__ dout_is,
                            float* __restrict__ pf4, int n) {
    int i = blockIdx.x * blockDim.x + threadIdx.x;
    if (i >= n) return;
    float s = dout_is[i];
    float4 v = *reinterpret_cast<const float4*>(x + (size_t)i * 4);
    float4 o = {v.x * s, v.y * s, v.z * s, v.w * s};
    *reinterpret_cast<float4*>(pf4 + (size_t)i * 4) = o;
}

__global__ void k_gather4(const float* __restrict__ pf4, const int* __restrict__ csr,
                          const unsigned* __restrict__ row_ptr, const float* __restrict__ din_is,
                          float* __restrict__ g, int n) {
    int i = blockIdx.x * blockDim.x + threadIdx.x;
    if (i >= n) return;
    unsigned beg = row_ptr[i], end = row_ptr[i + 1];
    float4 acc = {0.f, 0.f, 0.f, 0.f};
    unsigned e = beg;
    for (; e + 4 <= end; e += 4) {
        int s0 = csr[e], s1 = csr[e + 1], s2 = csr[e + 2], s3 = csr[e + 3];
        float4 v0 = *reinterpret_cast<const float4*>(pf4 + (size_t)s0 * 4);
        float4 v1 = *reinterpret_cast<const float4*>(pf4 + (size_t)s1 * 4);
        float4 v2 = *reinterpret_cast<const float4*>(pf4 + (size_t)s2 * 4);
        float4 v3 = *reinterpret_cast<const float4*>(pf4 + (size_t)s3 * 4);
        acc.x += (v0.x + v1.x) + (v2.x + v3.x);
        acc.y += (v0.y + v1.y) + (v2.y + v3.y);
        acc.z += (v0.z + v1.z) + (v2.z + v3.z);
        acc.w += (v0.w + v1.w) + (v2.w + v3.w);
    }
    for (; e < end; ++e) {
        int s = csr[e];
        float4 v = *reinterpret_cast<const float4*>(pf4 + (size_t)s * 4);
        acc.x += v.x; acc.y += v.y; acc.z += v.z; acc.w += v.w;
    }
    float di = din_is[i];
    float4 o = {acc.x * di, acc.y * di, acc.z * di, acc.w * di};
    *reinterpret_cast<float4*>(g + (size_t)i * 4) = o;
}

// xp1[i][j] = dout_is[i] * lrelu(g[i] . W1[:,j] + b1[j])
__global__ void k_lin1b(const float* __restrict__ g, const float* __restrict__ W,
                        const float* __restrict__ b, const float* __restrict__ dout_is,
                        float* __restrict__ xp, int n) {
    int t = blockIdx.x * blockDim.x + threadIdx.x;
    int i = t >> 7, j = t & 127;
    if (i >= n) return;
    float4 gv = *reinterpret_cast<const float4*>(g + (size_t)i * 4);
    float acc = gv.x * W[0 * 128 + j] + gv.y * W[1 * 128 + j] + gv.z * W[2 * 128 + j] + gv.w * W[3 * 128 + j];
    float v = acc + b[j];
    v = (v >= 0.f) ? v : LRELU_SLOPE * v;
    xp[(size_t)i * 128 + j] = v * dout_is[i];
}

// ---------------- fused middle layer ----------------

// Per 64-node tile: phase 1 gathers g = din_is * sum_in(xp) into LDS;
// phase 2 GEMM with W (wave-uniform scalar loads), epilogue
// xo = dout_is * lrelu(g@W + b)  (= next layer's prescaled input).
__global__ __launch_bounds__(512) void k_gl128(const float* __restrict__ xp, const int* __restrict__ csr,
                                               const unsigned* __restrict__ row_ptr,
                                               const float* __restrict__ din_is, const float* __restrict__ dout_is,
                                               const float* __restrict__ W, const float* __restrict__ b,
                                               float* __restrict__ xo, int n) {
    __shared__ float xs[64 * XPAD];  // 33 KB
    const int t = threadIdx.x;
    const int bbase = blockIdx.x * 64;
    const int wave = t >> 6;
    const int lane = t & 63;
    const int half = lane >> 5;
    const int j4 = (lane & 31) * 4;

    // phase 1: gather. wave w, half h -> rows 2w+h (+16 per sweep)
#pragma unroll
    for (int sweep = 0; sweep < 4; ++sweep) {
        int r = wave * 2 + half + sweep * 16;
        int node = bbase + r;
        float4 acc = {0.f, 0.f, 0.f, 0.f};
        if (node < n) {
            unsigned beg = row_ptr[node], end = row_ptr[node + 1];
            unsigned e = beg;
            for (; e + 4 <= end; e += 4) {
                int s0 = csr[e], s1 = csr[e + 1], s2 = csr[e + 2], s3 = csr[e + 3];
                float4 v0 = *reinterpret_cast<const float4*>(xp + (size_t)s0 * 128 + j4);
                float4 v1 = *reinterpret_cast<const float4*>(xp + (size_t)s1 * 128 + j4);
                float4 v2 = *reinterpret_cast<const float4*>(xp + (size_t)s2 * 128 + j4);
                float4 v3 = *reinterpret_cast<const float4*>(xp + (size_t)s3 * 128 + j4);
                acc.x += (v0.x + v1.x) + (v2.x + v3.x);
                acc.y += (v0.y + v1.y) + (v2.y + v3.y);
                acc.z += (v0.z + v1.z) + (v2.z + v3.z);
                acc.w += (v0.w + v1.w) + (v2.w + v3.w);
            }
            for (; e < end; ++e) {
                int s = csr[e];
                float4 v = *reinterpret_cast<const float4*>(xp + (size_t)s * 128 + j4);
                acc.x += v.x; acc.y += v.y; acc.z += v.z; acc.w += v.w;
            }
            float di = din_is[node];
            acc.x *= di; acc.y *= di; acc.z *= di; acc.w *= di;
        }
        float* d = xs + r * XPAD + j4;
        d[0] = acc.x; d[1] = acc.y; d[2] = acc.z; d[3] = acc.w;
    }
    __syncthreads();

    // phase 2: GEMM. lane = node, wave = 16-wide j tile.
    const int jg = __builtin_amdgcn_readfirstlane(wave) & 7;
    const int j0 = jg * 16;
    const float* Wj = W + j0;
    const float* xrow = xs + lane * XPAD;

    float acc[16];
#pragma unroll
    for (int q = 0; q < 16; ++q) acc[q] = 0.f;

#pragma unroll 2
    for (int k = 0; k < 128; k += 4) {
        float x0 = xrow[k + 0];
        float x1 = xrow[k + 1];
        float x2 = xrow[k + 2];
        float x3 = xrow[k + 3];
        const float* w0 = Wj + (size_t)k * 128;
#pragma unroll
        for (int q = 0; q < 16; ++q) {
            acc[q] += x0 * w0[q] + x1 * w0[128 + q] + x2 * w0[256 + q] + x3 * w0[384 + q];
        }
    }

    int node = bbase + lane;
    if (node < n) {
        float s = dout_is[node];
        float* out = xo + (size_t)node * 128 + j0;
#pragma unroll
        for (int q = 0; q < 16; q += 4) {
            float v0 = acc[q + 0] + b[j0 + q + 0];
            float v1 = acc[q + 1] + b[j0 + q + 1];
            float v2 = acc[q + 2] + b[j0 + q + 2];
            float v3 = acc[q + 3] + b[j0 + q + 3];
            v0 = (v0 >= 0.f) ? v0 : LRELU_SLOPE * v0;
            v1 = (v1 >= 0.f) ? v1 : LRELU_SLOPE * v1;
            v2 = (v2 >= 0.f) ? v2 : LRELU_SLOPE * v2;
            v3 = (v3 >= 0.f) ? v3 : LRELU_SLOPE * v3;
            float4 o = {v0 * s, v1 * s, v2 * s, v3 * s};
            *reinterpret_cast<float4*>(out + q) = o;
        }
    }
}

// ---------------- layer 5 ----------------

// input xp is already prescaled by dout_is
__global__ __launch_bounds__(256) void k_lin5v(const float* __restrict__ xp, const float* __restrict__ W,
                                               float* __restrict__ h, int n) {
    int node = blockIdx.x * 8 + (threadIdx.x >> 5);
    if (node >= n) return;
    int l = threadIdx.x & 31;
    int k4 = l * 4;
    float4 xv = *reinterpret_cast<const float4*>(xp + (size_t)node * 128 + k4);
    float4 wA = *reinterpret_cast<const float4*>(W + (size_t)k4 * 3);
    float4 wB = *reinterpret_cast<const float4*>(W + (size_t)k4 * 3 + 4);
    float4 wC = *reinterpret_cast<const float4*>(W + (size_t)k4 * 3 + 8);
    float p0 = xv.x * wA.x + xv.y * wA.w + xv.z * wB.z + xv.w * wC.y;
    float p1 = xv.x * wA.y + xv.y * wB.x + xv.z * wB.w + xv.w * wC.z;
    float p2 = xv.x * wA.z + xv.y * wB.y + xv.z * wC.x + xv.w * wC.w;
    for (int off = 16; off; off >>= 1) {
        p0 += __shfl_xor(p0, off, 32);
        p1 += __shfl_xor(p1, off, 32);
        p2 += __shfl_xor(p2, off, 32);
    }
    if (l == 0) {
        h[(size_t)node * 3 + 0] = p0;
        h[(size_t)node * 3 + 1] = p1;
        h[(size_t)node * 3 + 2] = p2;
    }
}

__global__ void k_gather3(const float* __restrict__ h, const int* __restrict__ csr,
                          const unsigned* __restrict__ row_ptr, const float* __restrict__ din_is,
                          const float* __restrict__ b, float* __restrict__ out, int n) {
    int i = blockIdx.x * blockDim.x + threadIdx.x;
    if (i >= n) return;
    unsigned beg = row_ptr[i], end = row_ptr[i + 1];
    float a0 = 0.f, a1 = 0.f, a2 = 0.f;
    for (unsigned e = beg; e < end; ++e) {
        int s = csr[e];
        a0 += h[(size_t)s * 3 + 0];
        a1 += h[(size_t)s * 3 + 1];
        a2 += h[(size_t)s * 3 + 2];
    }
    float di = din_is[i];
    out[(size_t)i * 3 + 0] = a0 * di + b[0];
    out[(size_t)i * 3 + 1] = a1 * di + b[1];
    out[(size_t)i * 3 + 2] = a2 * di + b[2];
}

// ---------------- launch ----------------

extern "C" void kernel_launch(void* const* d_in, const int* in_sizes, int n_in,
                              void* d_out, int out_size, void* d_ws, size_t ws_size,
                              hipStream_t stream) {
    const float* features = (const float*)d_in[0];
    const int* esrc = (const int*)d_in[1];
    const int* edst = (const int*)d_in[2];
    const float* W1 = (const float*)d_in[3];  const float* b1 = (const float*)d_in[4];
    const float* W2 = (const float*)d_in[5];  const float* b2 = (const float*)d_in[6];
    const float* W3 = (const float*)d_in[7];  const float* b3 = (const float*)d_in[8];
    const float* W4 = (const float*)d_in[9];  const float* b4 = (const float*)d_in[10];
    const float* W5 = (const float*)d_in[11]; const float* b5 = (const float*)d_in[12];

    const int N = in_sizes[0] / 4;
    const int E = in_sizes[1];

    size_t off = 0;
    auto carve = [&](size_t bytes) -> void* {
        void* p = (char*)d_ws + off;
        off = (off + bytes + 255) & ~(size_t)255;
        return p;
    };
    float*    A        = (float*)carve((size_t)N * 128 * 4);
    float*    B        = (float*)carve((size_t)N * 128 * 4);
    int*      csr      = (int*)carve((size_t)E * 4);
    unsigned* row_ptr  = (unsigned*)carve((size_t)(N + 1) * 4);
    unsigned* dout_cnt = (unsigned*)carve((size_t)N * 4);
    unsigned* din_cnt  = (unsigned*)carve((size_t)N * 4);
    float*    dout_is  = (float*)carve((size_t)N * 4);
    float*    din_is   = (float*)carve((size_t)N * 4);
    unsigned* scan_tmp = (unsigned*)carve((size_t)N * 4);
    unsigned* bsum     = (unsigned*)carve(4096);
    float*    h5       = (float*)carve((size_t)N * 3 * 4);
    (void)ws_size;
    // aliases: rank lives in A (consumed by csr_scatter before A's first
    // real use); pf4/g4 live in B (consumed by lin1b before B's first use)
    unsigned* rank = (unsigned*)A;
    float* pf4 = B;
    float* g4  = B + (size_t)N * 4;

    hipMemsetAsync(dout_cnt, 0, (size_t)N * 4, stream);
    hipMemsetAsync(din_cnt, 0, (size_t)N * 4, stream);

    k_degcount_rank<<<(E + 255) / 256, 256, 0, stream>>>(esrc, edst, E, dout_cnt, din_cnt, rank);
    k_invsqrt2<<<(N + 255) / 256, 256, 0, stream>>>(dout_cnt, dout_is, din_cnt, din_is, N);

    int nscan = (N + 255) / 256;
    k_scan_block<<<nscan, 256, 0, stream>>>(din_cnt, scan_tmp, bsum, N);
    k_scan_single<<<1, 1024, 0, stream>>>(bsum, nscan);
    k_finalize_rowptr<<<(N + 255) / 256, 256, 0, stream>>>(scan_tmp, bsum, row_ptr, N);
    k_csr_scatter<<<(E + 255) / 256, 256, 0, stream>>>(esrc, edst, E, row_ptr, rank, csr);

    // layer 1: aggregate 4-wide first, then 4->128 GEMM (+b+lrelu+prescale)
    k_prescale4<<<(N + 255) / 256, 256, 0, stream>>>(features, dout_is, pf4, N);
    k_gather4<<<(N + 255) / 256, 256, 0, stream>>>(pf4, csr, row_ptr, din_is, g4, N);
    k_lin1b<<<((size_t)N * 128 + 255) / 256, 256, 0, stream>>>(g4, W1, b1, dout_is, A, N);

    // layers 2-4 fused: gather + GEMM + epilogue
    int glGrid = (N + 63) / 64;
    k_gl128<<<glGrid, 512, 0, stream>>>(A, csr, row_ptr, din_is, dout_is, W2, b2, B, N);
    k_gl128<<<glGrid, 512, 0, stream>>>(B, csr, row_ptr, din_is, dout_is, W3, b3, A, N);
    k_gl128<<<glGrid, 512, 0, stream>>>(A, csr, row_ptr, din_is, dout_is, W4, b4, B, N);

    // layer 5: 128 -> 3 (input already prescaled), then 3-wide gather
    k_lin5v<<<(N + 7) / 8, 256, 0, stream>>>(B, W5, h5, N);
    k_gather3<<<(N + 255) / 256, 256, 0, stream>>>(h5, csr, row_ptr, din_is, b5, (float*)d_out, N);
}

// Round 5
// 738.223 us; speedup vs baseline: 2.1131x; 1.0177x over previous
//
#include <hip/hip_runtime.h>
#include <math.h>

// GraphConv x5 (DGL norm='both') on MI355X.
// xp-layer invariant: each layer's epilogue writes xp = dout_is * lrelu(y),
// i.e. the *prescaled* input of the next layer. Middle layers are fully
// fused: gather(xp)->LDS tile -> GEMM(W)+b+lrelu+prescale -> xp_next.
// CSR built with ONE atomic pass: rank[e] = atomicAdd(din_cnt[dst])'s old
// value gives each edge its slot; scatter pass is atomic-free.
// R5: gather inner loop 8-deep unroll, dual accumulators (8 in-flight
// 512B row loads per half-wave) — attacking gather latency-boundedness.

#define LRELU_SLOPE 0.01f
#define XPAD 129  // 128+1: LDS bank (lane+k)%32 -> 2-way on wave64 = free

// ---------------- preprocessing ----------------

__global__ void k_degcount_rank(const int* __restrict__ src, const int* __restrict__ dst,
                                int E, unsigned* __restrict__ dout_cnt,
                                unsigned* __restrict__ din_cnt, unsigned* __restrict__ rank) {
    int e = blockIdx.x * blockDim.x + threadIdx.x;
    if (e < E) {
        atomicAdd(&dout_cnt[src[e]], 1u);
        rank[e] = atomicAdd(&din_cnt[dst[e]], 1u);
    }
}

__global__ void k_invsqrt2(const unsigned* __restrict__ c0, float* __restrict__ i0,
                           const unsigned* __restrict__ c1, float* __restrict__ i1, int n) {
    int i = blockIdx.x * blockDim.x + threadIdx.x;
    if (i < n) {
        i0[i] = 1.0f / sqrtf(fmaxf((float)c0[i], 1.0f));
        i1[i] = 1.0f / sqrtf(fmaxf((float)c1[i], 1.0f));
    }
}

// blocked Hillis-Steele inclusive scan, 256/block
__global__ void k_scan_block(const unsigned* __restrict__ in, unsigned* __restrict__ out,
                             unsigned* __restrict__ bsum, int n) {
    __shared__ unsigned s[256];
    int g = blockIdx.x * 256 + threadIdx.x;
    unsigned v = (g < n) ? in[g] : 0u;
    s[threadIdx.x] = v;
    __syncthreads();
    for (int off = 1; off < 256; off <<= 1) {
        unsigned t = (threadIdx.x >= (unsigned)off) ? s[threadIdx.x - off] : 0u;
        __syncthreads();
        s[threadIdx.x] += t;
        __syncthreads();
    }
    if (g < n) out[g] = s[threadIdx.x];
    if (threadIdx.x == 255) bsum[blockIdx.x] = s[255];
}

__global__ void k_scan_single(unsigned* __restrict__ bsum, int n) {
    __shared__ unsigned s[1024];
    int t = threadIdx.x;
    s[t] = (t < n) ? bsum[t] : 0u;
    __syncthreads();
    for (int off = 1; off < 1024; off <<= 1) {
        unsigned v = (t >= off) ? s[t - off] : 0u;
        __syncthreads();
        s[t] += v;
        __syncthreads();
    }
    if (t < n) bsum[t] = (t == 0) ? 0u : s[t - 1];
}

__global__ void k_finalize_rowptr(const unsigned* __restrict__ scanned, const unsigned* __restrict__ boff,
                                  unsigned* __restrict__ row_ptr, int n) {
    int g = blockIdx.x * blockDim.x + threadIdx.x;
    if (g < n) row_ptr[g + 1] = scanned[g] + boff[g >> 8];
    if (g == 0) row_ptr[0] = 0u;
}

// atomic-free CSR fill using precomputed per-edge rank
__global__ void k_csr_scatter(const int* __restrict__ src, const int* __restrict__ dst, int E,
                              const unsigned* __restrict__ row_ptr, const unsigned* __restrict__ rank,
                              int* __restrict__ csr) {
    int e = blockIdx.x * blockDim.x + threadIdx.x;
    if (e < E) csr[row_ptr[dst[e]] + rank[e]] = src[e];
}

// ---------------- layer 1 (aggregate-first, 4-wide) ----------------

__global__ void k_prescale4(const float* __restrict__ x, const float* __restrict__ dout_is,
                            float* __restrict__ pf4, int n) {
    int i = blockIdx.x * blockDim.x + threadIdx.x;
    if (i >= n) return;
    float s = dout_is[i];
    float4 v = *reinterpret_cast<const float4*>(x + (size_t)i * 4);
    float4 o = {v.x * s, v.y * s, v.z * s, v.w * s};
    *reinterpret_cast<float4*>(pf4 + (size_t)i * 4) = o;
}

__global__ void k_gather4(const float* __restrict__ pf4, const int* __restrict__ csr,
                          const unsigned* __restrict__ row_ptr, const float* __restrict__ din_is,
                          float* __restrict__ g, int n) {
    int i = blockIdx.x * blockDim.x + threadIdx.x;
    if (i >= n) return;
    unsigned beg = row_ptr[i], end = row_ptr[i + 1];
    float4 acc = {0.f, 0.f, 0.f, 0.f};
    unsigned e = beg;
    for (; e + 4 <= end; e += 4) {
        int s0 = csr[e], s1 = csr[e + 1], s2 = csr[e + 2], s3 = csr[e + 3];
        float4 v0 = *reinterpret_cast<const float4*>(pf4 + (size_t)s0 * 4);
        float4 v1 = *reinterpret_cast<const float4*>(pf4 + (size_t)s1 * 4);
        float4 v2 = *reinterpret_cast<const float4*>(pf4 + (size_t)s2 * 4);
        float4 v3 = *reinterpret_cast<const float4*>(pf4 + (size_t)s3 * 4);
        acc.x += (v0.x + v1.x) + (v2.x + v3.x);
        acc.y += (v0.y + v1.y) + (v2.y + v3.y);
        acc.z += (v0.z + v1.z) + (v2.z + v3.z);
        acc.w += (v0.w + v1.w) + (v2.w + v3.w);
    }
    for (; e < end; ++e) {
        int s = csr[e];
        float4 v = *reinterpret_cast<const float4*>(pf4 + (size_t)s * 4);
        acc.x += v.x; acc.y += v.y; acc.z += v.z; acc.w += v.w;
    }
    float di = din_is[i];
    float4 o = {acc.x * di, acc.y * di, acc.z * di, acc.w * di};
    *reinterpret_cast<float4*>(g + (size_t)i * 4) = o;
}

// xp1[i][j] = dout_is[i] * lrelu(g[i] . W1[:,j] + b1[j])
__global__ void k_lin1b(const float* __restrict__ g, const float* __restrict__ W,
                        const float* __restrict__ b, const float* __restrict__ dout_is,
                        float* __restrict__ xp, int n) {
    int t = blockIdx.x * blockDim.x + threadIdx.x;
    int i = t >> 7, j = t & 127;
    if (i >= n) return;
    float4 gv = *reinterpret_cast<const float4*>(g + (size_t)i * 4);
    float acc = gv.x * W[0 * 128 + j] + gv.y * W[1 * 128 + j] + gv.z * W[2 * 128 + j] + gv.w * W[3 * 128 + j];
    float v = acc + b[j];
    v = (v >= 0.f) ? v : LRELU_SLOPE * v;
    xp[(size_t)i * 128 + j] = v * dout_is[i];
}

// ---------------- fused middle layer ----------------

// Per 64-node tile: phase 1 gathers g = din_is * sum_in(xp) into LDS;
// phase 2 GEMM with W (wave-uniform scalar loads), epilogue
// xo = dout_is * lrelu(g@W + b)  (= next layer's prescaled input).
__global__ __launch_bounds__(512) void k_gl128(const float* __restrict__ xp, const int* __restrict__ csr,
                                               const unsigned* __restrict__ row_ptr,
                                               const float* __restrict__ din_is, const float* __restrict__ dout_is,
                                               const float* __restrict__ W, const float* __restrict__ b,
                                               float* __restrict__ xo, int n) {
    __shared__ float xs[64 * XPAD];  // 33 KB
    const int t = threadIdx.x;
    const int bbase = blockIdx.x * 64;
    const int wave = t >> 6;
    const int lane = t & 63;
    const int half = lane >> 5;
    const int j4 = (lane & 31) * 4;

    // phase 1: gather. wave w, half h -> rows 2w+h (+16 per sweep).
    // 8-edge unroll, dual accumulators: 8 independent 512B row loads in
    // flight per half-wave (latency hiding).
#pragma unroll
    for (int sweep = 0; sweep < 4; ++sweep) {
        int r = wave * 2 + half + sweep * 16;
        int node = bbase + r;
        float4 accA = {0.f, 0.f, 0.f, 0.f};
        float4 accB = {0.f, 0.f, 0.f, 0.f};
        if (node < n) {
            unsigned beg = row_ptr[node], end = row_ptr[node + 1];
            unsigned e = beg;
            for (; e + 8 <= end; e += 8) {
                int s0 = csr[e + 0], s1 = csr[e + 1], s2 = csr[e + 2], s3 = csr[e + 3];
                int s4 = csr[e + 4], s5 = csr[e + 5], s6 = csr[e + 6], s7 = csr[e + 7];
                float4 v0 = *reinterpret_cast<const float4*>(xp + (size_t)s0 * 128 + j4);
                float4 v1 = *reinterpret_cast<const float4*>(xp + (size_t)s1 * 128 + j4);
                float4 v2 = *reinterpret_cast<const float4*>(xp + (size_t)s2 * 128 + j4);
                float4 v3 = *reinterpret_cast<const float4*>(xp + (size_t)s3 * 128 + j4);
                float4 v4 = *reinterpret_cast<const float4*>(xp + (size_t)s4 * 128 + j4);
                float4 v5 = *reinterpret_cast<const float4*>(xp + (size_t)s5 * 128 + j4);
                float4 v6 = *reinterpret_cast<const float4*>(xp + (size_t)s6 * 128 + j4);
                float4 v7 = *reinterpret_cast<const float4*>(xp + (size_t)s7 * 128 + j4);
                accA.x += (v0.x + v1.x) + (v2.x + v3.x);
                accA.y += (v0.y + v1.y) + (v2.y + v3.y);
                accA.z += (v0.z + v1.z) + (v2.z + v3.z);
                accA.w += (v0.w + v1.w) + (v2.w + v3.w);
                accB.x += (v4.x + v5.x) + (v6.x + v7.x);
                accB.y += (v4.y + v5.y) + (v6.y + v7.y);
                accB.z += (v4.z + v5.z) + (v6.z + v7.z);
                accB.w += (v4.w + v5.w) + (v6.w + v7.w);
            }
            if (e + 4 <= end) {
                int s0 = csr[e + 0], s1 = csr[e + 1], s2 = csr[e + 2], s3 = csr[e + 3];
                float4 v0 = *reinterpret_cast<const float4*>(xp + (size_t)s0 * 128 + j4);
                float4 v1 = *reinterpret_cast<const float4*>(xp + (size_t)s1 * 128 + j4);
                float4 v2 = *reinterpret_cast<const float4*>(xp + (size_t)s2 * 128 + j4);
                float4 v3 = *reinterpret_cast<const float4*>(xp + (size_t)s3 * 128 + j4);
                accA.x += (v0.x + v1.x) + (v2.x + v3.x);
                accA.y += (v0.y + v1.y) + (v2.y + v3.y);
                accA.z += (v0.z + v1.z) + (v2.z + v3.z);
                accA.w += (v0.w + v1.w) + (v2.w + v3.w);
                e += 4;
            }
            for (; e < end; ++e) {
                int s = csr[e];
                float4 v = *reinterpret_cast<const float4*>(xp + (size_t)s * 128 + j4);
                accB.x += v.x; accB.y += v.y; accB.z += v.z; accB.w += v.w;
            }
            float di = din_is[node];
            accA.x = (accA.x + accB.x) * di;
            accA.y = (accA.y + accB.y) * di;
            accA.z = (accA.z + accB.z) * di;
            accA.w = (accA.w + accB.w) * di;
        }
        float* d = xs + r * XPAD + j4;
        d[0] = accA.x; d[1] = accA.y; d[2] = accA.z; d[3] = accA.w;
    }
    __syncthreads();

    // phase 2: GEMM. lane = node, wave = 16-wide j tile.
    const int jg = __builtin_amdgcn_readfirstlane(wave) & 7;
    const int j0 = jg * 16;
    const float* Wj = W + j0;
    const float* xrow = xs + lane * XPAD;

    float acc[16];
#pragma unroll
    for (int q = 0; q < 16; ++q) acc[q] = 0.f;

#pragma unroll 2
    for (int k = 0; k < 128; k += 4) {
        float x0 = xrow[k + 0];
        float x1 = xrow[k + 1];
        float x2 = xrow[k + 2];
        float x3 = xrow[k + 3];
        const float* w0 = Wj + (size_t)k * 128;
#pragma unroll
        for (int q = 0; q < 16; ++q) {
            acc[q] += x0 * w0[q] + x1 * w0[128 + q] + x2 * w0[256 + q] + x3 * w0[384 + q];
        }
    }

    int node = bbase + lane;
    if (node < n) {
        float s = dout_is[node];
        float* out = xo + (size_t)node * 128 + j0;
#pragma unroll
        for (int q = 0; q < 16; q += 4) {
            float v0 = acc[q + 0] + b[j0 + q + 0];
            float v1 = acc[q + 1] + b[j0 + q + 1];
            float v2 = acc[q + 2] + b[j0 + q + 2];
            float v3 = acc[q + 3] + b[j0 + q + 3];
            v0 = (v0 >= 0.f) ? v0 : LRELU_SLOPE * v0;
            v1 = (v1 >= 0.f) ? v1 : LRELU_SLOPE * v1;
            v2 = (v2 >= 0.f) ? v2 : LRELU_SLOPE * v2;
            v3 = (v3 >= 0.f) ? v3 : LRELU_SLOPE * v3;
            float4 o = {v0 * s, v1 * s, v2 * s, v3 * s};
            *reinterpret_cast<float4*>(out + q) = o;
        }
    }
}

// ---------------- layer 5 ----------------

// input xp is already prescaled by dout_is
__global__ __launch_bounds__(256) void k_lin5v(const float* __restrict__ xp, const float* __restrict__ W,
                                               float* __restrict__ h, int n) {
    int node = blockIdx.x * 8 + (threadIdx.x >> 5);
    if (node >= n) return;
    int l = threadIdx.x & 31;
    int k4 = l * 4;
    float4 xv = *reinterpret_cast<const float4*>(xp + (size_t)node * 128 + k4);
    float4 wA = *reinterpret_cast<const float4*>(W + (size_t)k4 * 3);
    float4 wB = *reinterpret_cast<const float4*>(W + (size_t)k4 * 3 + 4);
    float4 wC = *reinterpret_cast<const float4*>(W + (size_t)k4 * 3 + 8);
    float p0 = xv.x * wA.x + xv.y * wA.w + xv.z * wB.z + xv.w * wC.y;
    float p1 = xv.x * wA.y + xv.y * wB.x + xv.z * wB.w + xv.w * wC.z;
    float p2 = xv.x * wA.z + xv.y * wB.y + xv.z * wC.x + xv.w * wC.w;
    for (int off = 16; off; off >>= 1) {
        p0 += __shfl_xor(p0, off, 32);
        p1 += __shfl_xor(p1, off, 32);
        p2 += __shfl_xor(p2, off, 32);
    }
    if (l == 0) {
        h[(size_t)node * 3 + 0] = p0;
        h[(size_t)node * 3 + 1] = p1;
        h[(size_t)node * 3 + 2] = p2;
    }
}

__global__ void k_gather3(const float* __restrict__ h, const int* __restrict__ csr,
                          const unsigned* __restrict__ row_ptr, const float* __restrict__ din_is,
                          const float* __restrict__ b, float* __restrict__ out, int n) {
    int i = blockIdx.x * blockDim.x + threadIdx.x;
    if (i >= n) return;
    unsigned beg = row_ptr[i], end = row_ptr[i + 1];
    float a0 = 0.f, a1 = 0.f, a2 = 0.f;
    for (unsigned e = beg; e < end; ++e) {
        int s = csr[e];
        a0 += h[(size_t)s * 3 + 0];
        a1 += h[(size_t)s * 3 + 1];
        a2 += h[(size_t)s * 3 + 2];
    }
    float di = din_is[i];
    out[(size_t)i * 3 + 0] = a0 * di + b[0];
    out[(size_t)i * 3 + 1] = a1 * di + b[1];
    out[(size_t)i * 3 + 2] = a2 * di + b[2];
}

// ---------------- launch ----------------

extern "C" void kernel_launch(void* const* d_in, const int* in_sizes, int n_in,
                              void* d_out, int out_size, void* d_ws, size_t ws_size,
                              hipStream_t stream) {
    const float* features = (const float*)d_in[0];
    const int* esrc = (const int*)d_in[1];
    const int* edst = (const int*)d_in[2];
    const float* W1 = (const float*)d_in[3];  const float* b1 = (const float*)d_in[4];
    const float* W2 = (const float*)d_in[5];  const float* b2 = (const float*)d_in[6];
    const float* W3 = (const float*)d_in[7];  const float* b3 = (const float*)d_in[8];
    const float* W4 = (const float*)d_in[9];  const float* b4 = (const float*)d_in[10];
    const float* W5 = (const float*)d_in[11]; const float* b5 = (const float*)d_in[12];

    const int N = in_sizes[0] / 4;
    const int E = in_sizes[1];

    size_t off = 0;
    auto carve = [&](size_t bytes) -> void* {
        void* p = (char*)d_ws + off;
        off = (off + bytes + 255) & ~(size_t)255;
        return p;
    };
    float*    A        = (float*)carve((size_t)N * 128 * 4);
    float*    B        = (float*)carve((size_t)N * 128 * 4);
    int*      csr      = (int*)carve((size_t)E * 4);
    unsigned* row_ptr  = (unsigned*)carve((size_t)(N + 1) * 4);
    unsigned* dout_cnt = (unsigned*)carve((size_t)N * 4);
    unsigned* din_cnt  = (unsigned*)carve((size_t)N * 4);
    float*    dout_is  = (float*)carve((size_t)N * 4);
    float*    din_is   = (float*)carve((size_t)N * 4);
    unsigned* scan_tmp = (unsigned*)carve((size_t)N * 4);
    unsigned* bsum     = (unsigned*)carve(4096);
    float*    h5       = (float*)carve((size_t)N * 3 * 4);
    (void)ws_size;
    // aliases: rank lives in A (consumed by csr_scatter before A's first
    // real use); pf4/g4 live in B (consumed by lin1b before B's first use)
    unsigned* rank = (unsigned*)A;
    float* pf4 = B;
    float* g4  = B + (size_t)N * 4;

    hipMemsetAsync(dout_cnt, 0, (size_t)N * 4, stream);
    hipMemsetAsync(din_cnt, 0, (size_t)N * 4, stream);

    k_degcount_rank<<<(E + 255) / 256, 256, 0, stream>>>(esrc, edst, E, dout_cnt, din_cnt, rank);
    k_invsqrt2<<<(N + 255) / 256, 256, 0, stream>>>(dout_cnt, dout_is, din_cnt, din_is, N);

    int nscan = (N + 255) / 256;
    k_scan_block<<<nscan, 256, 0, stream>>>(din_cnt, scan_tmp, bsum, N);
    k_scan_single<<<1, 1024, 0, stream>>>(bsum, nscan);
    k_finalize_rowptr<<<(N + 255) / 256, 256, 0, stream>>>(scan_tmp, bsum, row_ptr, N);
    k_csr_scatter<<<(E + 255) / 256, 256, 0, stream>>>(esrc, edst, E, row_ptr, rank, csr);

    // layer 1: aggregate 4-wide first, then 4->128 GEMM (+b+lrelu+prescale)
    k_prescale4<<<(N + 255) / 256, 256, 0, stream>>>(features, dout_is, pf4, N);
    k_gather4<<<(N + 255) / 256, 256, 0, stream>>>(pf4, csr, row_ptr, din_is, g4, N);
    k_lin1b<<<((size_t)N * 128 + 255) / 256, 256, 0, stream>>>(g4, W1, b1, dout_is, A, N);

    // layers 2-4 fused: gather + GEMM + epilogue
    int glGrid = (N + 63) / 64;
    k_gl128<<<glGrid, 512, 0, stream>>>(A, csr, row_ptr, din_is, dout_is, W2, b2, B, N);
    k_gl128<<<glGrid, 512, 0, stream>>>(B, csr, row_ptr, din_is, dout_is, W3, b3, A, N);
    k_gl128<<<glGrid, 512, 0, stream>>>(A, csr, row_ptr, din_is, dout_is, W4, b4, B, N);

    // layer 5: 128 -> 3 (input already prescaled), then 3-wide gather
    k_lin5v<<<(N + 7) / 8, 256, 0, stream>>>(B, W5, h5, N);
    k_gather3<<<(N + 255) / 256, 256, 0, stream>>>(h5, csr, row_ptr, din_is, b5, (float*)d_out, N);
}